// Round 8
// baseline (491.476 us; speedup 1.0000x reference)
//
#include <hip/hip_runtime.h>
#include <hip/hip_fp16.h>
#include <cstdint>

#define NN 50000
#define NQBLK8 1563             // k_q blocks: NN*8/256 rounded up
#define NGBLK4 3125             // gather blocks: 16 nodes/block (4 per wave)
#define EPSV 1e-5f

// bucket sort params
#define NPB 128                 // nodes per bucket
#define BSH 7                   // log2(NPB)
#define NBKT 391                // ceil(NN/NPB)
#define CHUNK 4096              // edges per stage-1 block
#define EPT 16                  // edges per thread (CHUNK/256)
#define LDSE 6144               // per-bucket LDS edge capacity

// BN partial-sum spreading: 128 slots x 8 floats per layer (64 cache lines).
// R9/R10: hot-line atomics cost ~120us; spread over 64 lines -> negligible.
#define NSLOT 128

typedef unsigned short ushort_t;
typedef _Float16 half2v __attribute__((ext_vector_type(2)));

// ---------------- stage 1: per-chunk bucket histogram (+ zero BN slots) ----------------
__global__ __launch_bounds__(256) void k_hist1(const int* __restrict__ dst, int E, int nchunk,
                                               int* __restrict__ hist, float* __restrict__ gsumsp) {
    __shared__ int cnt[NBKT];
    int t = threadIdx.x, blk = blockIdx.x;
    if (blk == 0) {
        for (int z = t; z < 5 * NSLOT * 8; z += 256) gsumsp[z] = 0.f;
    }
    for (int b = t; b < NBKT; b += 256) cnt[b] = 0;
    __syncthreads();
    int base = blk * CHUNK;
#pragma unroll
    for (int k = 0; k < EPT; ++k) {
        int e = base + k * 256 + t;
        if (e < E) atomicAdd(&cnt[dst[e] >> BSH], 1);
    }
    __syncthreads();
    for (int b = t; b < NBKT; b += 256) hist[(size_t)b * nchunk + blk] = cnt[b];
}

// ---------------- hierarchical exclusive scan (A: per-block, C: fused apply) ----------------
__global__ __launch_bounds__(256) void k_scanA(const int* __restrict__ in, int n,
                                               int* __restrict__ presum, int* __restrict__ blocksum) {
    __shared__ int lds[256];
    int t = threadIdx.x, g = blockIdx.x * 256 + t;
    int v = (g < n) ? in[g] : 0;
    lds[t] = v;
    __syncthreads();
    for (int off = 1; off < 256; off <<= 1) {
        int x = (t >= off) ? lds[t - off] : 0;
        __syncthreads();
        lds[t] += x;
        __syncthreads();
    }
    if (g < n) presum[g] = lds[t];
    if (t == 255) blocksum[blockIdx.x] = lds[255];
}

// fused scanB+scanC: each block computes its own carry (sum of blocksum[0..blk))
__global__ __launch_bounds__(256) void k_scanC(const int* __restrict__ presum,
                                               const int* __restrict__ hist,
                                               const int* __restrict__ blocksum,
                                               int n, int nchunk, int* __restrict__ offsT) {
    __shared__ int lds[256];
    int t = threadIdx.x, myblk = blockIdx.x;
    int acc = 0;
    for (int i = t; i < myblk; i += 256) acc += blocksum[i];
    lds[t] = acc;
    __syncthreads();
    for (int off = 128; off > 0; off >>= 1) {
        if (t < off) lds[t] += lds[t + off];
        __syncthreads();
    }
    int boff = lds[0];
    int g = myblk * 256 + t;
    if (g < n) {
        int val = presum[g] - hist[g] + boff;
        int b = g / nchunk;
        int c = g - b * nchunk;
        offsT[(size_t)c * NBKT + b] = val;
    }
}

// ---------------- stage 1: partition edges into buckets ----------------
__global__ __launch_bounds__(256) void k_scatter1(const int* __restrict__ src,
                                                  const int* __restrict__ dst, int E,
                                                  const int* __restrict__ offsT,
                                                  int* __restrict__ ebuf) {
    __shared__ int pos[NBKT];
    int t = threadIdx.x, blk = blockIdx.x;
    for (int b = t; b < NBKT; b += 256) pos[b] = offsT[(size_t)blk * NBKT + b];
    __syncthreads();
    int base = blk * CHUNK;
#pragma unroll
    for (int k = 0; k < EPT; ++k) {
        int e = base + k * 256 + t;
        if (e < E) {
            int d = dst[e];
            int b = d >> BSH;
            int p = atomicAdd(&pos[b], 1);
            ebuf[p] = ((d & (NPB - 1)) << 16) | src[e];
        }
    }
}

// ---------------- stage 2: per-bucket CSR ----------------
__global__ __launch_bounds__(256) void k_bucket_csr(const int* __restrict__ ebuf,
                                                    const int* __restrict__ offsT, int E,
                                                    int* __restrict__ rowstart,
                                                    ushort_t* __restrict__ colsrc) {
    __shared__ int cnt[NPB];
    __shared__ int s[NPB];
    __shared__ int pos2[NPB];
    __shared__ ushort_t lout[LDSE];
    int t = threadIdx.x, b = blockIdx.x;
    int bstart = offsT[b];
    int bend = (b + 1 < NBKT) ? offsT[b + 1] : E;
    int m = bend - bstart;
    if (t < NPB) cnt[t] = 0;
    __syncthreads();
    for (int i = bstart + t; i < bend; i += 256) atomicAdd(&cnt[ebuf[i] >> 16], 1);
    __syncthreads();
    if (t < NPB) s[t] = cnt[t];
    __syncthreads();
    for (int off = 1; off < NPB; off <<= 1) {
        int x = (t < NPB && t >= off) ? s[t - off] : 0;
        __syncthreads();
        if (t < NPB) s[t] += x;
        __syncthreads();
    }
    if (t < NPB) {
        int excl = s[t] - cnt[t];
        int node = b * NPB + t;
        if (node < NN) rowstart[node] = bstart + excl;
        pos2[t] = excl;
    }
    __syncthreads();
    if (m <= LDSE) {
        for (int i = bstart + t; i < bend; i += 256) {
            int v = ebuf[i];
            int p = atomicAdd(&pos2[v >> 16], 1);
            lout[p] = (ushort_t)(v & 0xFFFF);
        }
        __syncthreads();
        for (int i = t; i < m; i += 256) colsrc[bstart + i] = lout[i];
    } else {
        for (int i = bstart + t; i < bend; i += 256) {
            int v = ebuf[i];
            int p = atomicAdd(&pos2[v >> 16], 1);
            colsrc[bstart + p] = (ushort_t)(v & 0xFFFF);
        }
    }
    if (b == NBKT - 1 && t == 0) rowstart[NN] = E;
}

// ---------------- per-layer: node -> (q_s, q_d), BN-finalize fused in-block ----------------
__global__ __launch_bounds__(256) void k_q(
    const float* __restrict__ pin, int pstride, int c0, int c1, int c2,
    const float* __restrict__ W1l, const float* __restrict__ b1l,
    const float* __restrict__ gsum_prev, const float* __restrict__ gamma_l,
    const float* __restrict__ beta_l, int use_bn,
    __half* __restrict__ qs, __half* __restrict__ qd) {
    __shared__ float red[6][8];
    __shared__ float scv[3], shv[3];
    int tid = threadIdx.x;
    if (use_bn) {
        if (tid < 48) {
            int j = tid >> 3, k = tid & 7;
            float s = 0.f;
            for (int slot = k; slot < NSLOT; slot += 8) s += gsum_prev[slot * 8 + j];
            red[j][k] = s;
        }
        __syncthreads();
        if (tid < 3) {
            const int cols[3] = {0, 1, 14};
            float sum = 0.f, sumsq = 0.f;
#pragma unroll
            for (int k2 = 0; k2 < 8; ++k2) { sum += red[tid][k2]; sumsq += red[tid + 3][k2]; }
            float mu = sum / (float)NN;
            float var = sumsq / (float)NN - mu * mu;
            float rs = rsqrtf(var + EPSV);
            float g = gamma_l[cols[tid]];
            scv[tid] = rs * g;
            shv[tid] = beta_l[cols[tid]] - mu * rs * g;
        }
        __syncthreads();
    }
    int idx = blockIdx.x * 256 + tid;
    int v = idx >> 3, g = idx & 7;
    if (v >= NN) return;
    const float* prow = pin + (size_t)v * pstride;
    float p0 = prow[c0], p1 = prow[c1], p2 = prow[c2];
    if (use_bn) {
        p0 = fmaxf(0.f, p0 * scv[0] + shv[0]);
        p1 = fmaxf(0.f, p1 * scv[1] + shv[1]);
        p2 = fmaxf(0.f, p2 * scv[2] + shv[2]);
    }
    unsigned int us[4], ud[4];
#pragma unroll
    for (int pr = 0; pr < 4; ++pr) {
        int c = (g << 3) + (pr << 1);
        float w0a = W1l[c], w1a = W1l[64 + c], w2a = W1l[128 + c];
        float qsa = p0 * w0a + p1 * w1a + p2 * w2a;
        float qda = p0 * (W1l[192 + c] - w0a) + p1 * (W1l[256 + c] - w1a)
                  + p2 * (W1l[320 + c] - w2a) + b1l[c];
        int c1i = c + 1;
        float w0b = W1l[c1i], w1b = W1l[64 + c1i], w2b = W1l[128 + c1i];
        float qsb = p0 * w0b + p1 * w1b + p2 * w2b;
        float qdb = p0 * (W1l[192 + c1i] - w0b) + p1 * (W1l[256 + c1i] - w1b)
                  + p2 * (W1l[320 + c1i] - w2b) + b1l[c1i];
        us[pr] = (unsigned int)__half_as_ushort(__float2half(qsa))
               | ((unsigned int)__half_as_ushort(__float2half(qsb)) << 16);
        ud[pr] = (unsigned int)__half_as_ushort(__float2half(qda))
               | ((unsigned int)__half_as_ushort(__float2half(qdb)) << 16);
    }
    uint4 vs = {us[0], us[1], us[2], us[3]};
    uint4 vd = {ud[0], ud[1], ud[2], ud[3]};
    ((uint4*)qs)[(size_t)v * 8 + g] = vs;
    ((uint4*)qd)[(size_t)v * 8 + g] = vd;
}

// ---------------- edge accumulation helpers ----------------
// R9: no per-load branches; masked slots load row 0 (L1-hot, no MSHR cost).
// R20: 4 nodes/wave, 16-slot chunks; one colsrc load covers all 4 nodes.
// R21: 2-deep software pipeline — iteration i+1's 8 gather loads are ISSUED
// before iteration i's math (double-buffered q regs), colsrc prefetched two
// iterations ahead. Keeps ~8 lines continuously in flight per wave.
__device__ __forceinline__ half2v bitcast_h2(unsigned int u) {
    union { unsigned int u; half2v h; } cvt;
    cvt.u = u;
    return cvt.h;
}

__device__ __forceinline__ void accum8f(const char* __restrict__ qsb, unsigned int byteoff,
                                        const half2v qd2[4], float acc[8]) {
    uint4 q = *reinterpret_cast<const uint4*>(qsb + byteoff);
    unsigned int wd[4] = {q.x, q.y, q.z, q.w};
    const half2v z2 = {(_Float16)0.0f, (_Float16)0.0f};
#pragma unroll
    for (int d = 0; d < 4; ++d) {
        half2v r = bitcast_h2(wd[d]) + qd2[d];
        r = __builtin_elementwise_max(r, z2);
        acc[2 * d]     += (float)r.x;
        acc[2 * d + 1] += (float)r.y;
    }
}

__device__ __forceinline__ void chunk_math16(const uint4 q[2], const half2v qd2[4],
                                             int r, int es, float acc[8]) {
    const half2v z2 = {(_Float16)0.0f, (_Float16)0.0f};
    half2v h[4] = {z2, z2, z2, z2};
#pragma unroll
    for (int k = 0; k < 2; ++k) {
        bool ok = ((k << 3) + es) < r;
        unsigned int wd[4] = {q[k].x, q[k].y, q[k].z, q[k].w};
#pragma unroll
        for (int d = 0; d < 4; ++d) {
            half2v t = bitcast_h2(wd[d]) + qd2[d];      // v_pk_add_f16
            t = __builtin_elementwise_max(t, z2);       // v_pk_max_f16
            h[d] += ok ? t : z2;                        // cndmask + pk_add
        }
    }
#pragma unroll
    for (int d = 0; d < 4; ++d) {
        acc[2 * d]     += (float)h[d].x;
        acc[2 * d + 1] += (float)h[d].y;
    }
}

__device__ __forceinline__ int clamp16(int x) { return x < 16 ? (x < 0 ? 0 : x) : 16; }

#define GATHER4(QA, QB, QC, QD, SL)                                                          \
    {                                                                                        \
        _Pragma("unroll") for (int k = 0; k < 2; ++k) {                                      \
            int s = __shfl(SL, 0 * 16 + (k << 3) + es);                                      \
            QA[k] = *reinterpret_cast<const uint4*>(qsb + (((unsigned int)(s << 7)) | cg16));\
        }                                                                                    \
        _Pragma("unroll") for (int k = 0; k < 2; ++k) {                                      \
            int s = __shfl(SL, 1 * 16 + (k << 3) + es);                                      \
            QB[k] = *reinterpret_cast<const uint4*>(qsb + (((unsigned int)(s << 7)) | cg16));\
        }                                                                                    \
        _Pragma("unroll") for (int k = 0; k < 2; ++k) {                                      \
            int s = __shfl(SL, 2 * 16 + (k << 3) + es);                                      \
            QC[k] = *reinterpret_cast<const uint4*>(qsb + (((unsigned int)(s << 7)) | cg16));\
        }                                                                                    \
        _Pragma("unroll") for (int k = 0; k < 2; ++k) {                                      \
            int s = __shfl(SL, 3 * 16 + (k << 3) + es);                                      \
            QD[k] = *reinterpret_cast<const uint4*>(qsb + (((unsigned int)(s << 7)) | cg16));\
        }                                                                                    \
    }

#define MATH4(QA, QB, QC, QD, R0, R1, R2, R3)                                                \
    {                                                                                        \
        chunk_math16(QA, qd2a, R0, es, accA);                                                \
        chunk_math16(QB, qd2b, R1, es, accB);                                                \
        chunk_math16(QC, qd2c, R2, es, accC);                                                \
        chunk_math16(QD, qd2d, R3, es, accD);                                                \
    }

#define CSLOAD(P0, P1, P2, P3, R0, R1, R2, R3)                                               \
    ((o < ((g == 0) ? (R0) : (g == 1) ? (R1) : (g == 2) ? (R2) : (R3)))                      \
         ? (int)colsrc[((g == 0) ? (P0) : (g == 1) ? (P1) : (g == 2) ? (P2) : (P3)) + o]     \
         : 0)

// quad loop, 2-deep pipelined. Nodes 0..3 with CSR ranges [i_k, e_k).
__device__ __forceinline__ void quad_edge_loop(const char* __restrict__ qsb,
                                               const ushort_t* __restrict__ colsrc,
                                               int i0, int e0, int i1, int e1,
                                               int i2, int e2, int i3, int e3,
                                               int lane, int es, unsigned int cg16,
                                               const half2v qd2a[4], const half2v qd2b[4],
                                               const half2v qd2c[4], const half2v qd2d[4],
                                               float accA[8], float accB[8],
                                               float accC[8], float accD[8]) {
    int g = lane >> 4, o = lane & 15;
    // current iteration state
    int rc0 = clamp16(e0 - i0), rc1 = clamp16(e1 - i1);
    int rc2 = clamp16(e2 - i2), rc3 = clamp16(e3 - i3);
    if ((rc0 | rc1 | rc2 | rc3) == 0) return;
    // next state
    int pn0 = i0 + rc0, pn1 = i1 + rc1, pn2 = i2 + rc2, pn3 = i3 + rc3;
    int rn0 = clamp16(e0 - pn0), rn1 = clamp16(e1 - pn1);
    int rn2 = clamp16(e2 - pn2), rn3 = clamp16(e3 - pn3);
    bool moreN = (rn0 | rn1 | rn2 | rn3) != 0;
    // next-next state
    int pm0 = pn0 + rn0, pm1 = pn1 + rn1, pm2 = pn2 + rn2, pm3 = pn3 + rn3;
    int rm0 = clamp16(e0 - pm0), rm1 = clamp16(e1 - pm1);
    int rm2 = clamp16(e2 - pm2), rm3 = clamp16(e3 - pm3);
    bool moreM = (rm0 | rm1 | rm2 | rm3) != 0;
    // issue all three colsrc loads up front
    int slC = CSLOAD(i0, i1, i2, i3, rc0, rc1, rc2, rc3);
    int slN = moreN ? CSLOAD(pn0, pn1, pn2, pn3, rn0, rn1, rn2, rn3) : 0;
    int slM = moreM ? CSLOAD(pm0, pm1, pm2, pm3, rm0, rm1, rm2, rm3) : 0;

    uint4 qA0[2], qB0[2], qC0[2], qD0[2];   // buffer 0
    uint4 qA1[2], qB1[2], qC1[2], qD1[2];   // buffer 1
    GATHER4(qA0, qB0, qC0, qD0, slC);

#define ROTATE()                                                                             \
    {                                                                                        \
        rc0 = rn0; rc1 = rn1; rc2 = rn2; rc3 = rn3;                                          \
        pn0 = pm0; pn1 = pm1; pn2 = pm2; pn3 = pm3;                                          \
        rn0 = rm0; rn1 = rm1; rn2 = rm2; rn3 = rm3;                                          \
        slN = slM; moreN = moreM;                                                            \
        pm0 = pn0 + rn0; pm1 = pn1 + rn1; pm2 = pn2 + rn2; pm3 = pn3 + rn3;                  \
        rm0 = clamp16(e0 - pm0); rm1 = clamp16(e1 - pm1);                                    \
        rm2 = clamp16(e2 - pm2); rm3 = clamp16(e3 - pm3);                                    \
        moreM = (rm0 | rm1 | rm2 | rm3) != 0;                                                \
        if (moreM) slM = CSLOAD(pm0, pm1, pm2, pm3, rm0, rm1, rm2, rm3);                     \
    }

    while (true) {
        // half 1: buffer0 is current, buffer1 is being filled
        if (moreN) GATHER4(qA1, qB1, qC1, qD1, slN);
        MATH4(qA0, qB0, qC0, qD0, rc0, rc1, rc2, rc3);
        if (!moreN) break;
        ROTATE();
        // half 2: buffer1 is current, buffer0 is being filled
        if (moreN) GATHER4(qA0, qB0, qC0, qD0, slN);
        MATH4(qA1, qB1, qC1, qD1, rc0, rc1, rc2, rc3);
        if (!moreN) break;
        ROTATE();
    }
#undef ROTATE
}

// ---------------- gather + reduce, layers 0..4 (3 output cols), 4 nodes/wave ----------------
__global__ __launch_bounds__(256) void k_gather3(
    const __half* __restrict__ qs, const __half* __restrict__ qd,
    const int* __restrict__ rowstart, const ushort_t* __restrict__ colsrc,
    const float* __restrict__ W2l, const float* __restrict__ b2l,
    float* __restrict__ pnext, float* __restrict__ gsum_l) {
    __shared__ float w2c[3][64];
    __shared__ float b2c[3];
    __shared__ float part[4][8];
    int tid = threadIdx.x;
    if (tid < 192) {
        int cj = tid >> 6;
        int col = (cj == 0) ? 0 : ((cj == 1) ? 1 : 14);
        w2c[cj][tid & 63] = W2l[(tid & 63) * 64 + col];
    }
    if (tid < 3) b2c[tid] = b2l[(tid == 0) ? 0 : ((tid == 1) ? 1 : 14)];
    __syncthreads();

    int w = tid >> 6, lane = tid & 63;
    int es = lane >> 3, cg = lane & 7;
    unsigned int cg16 = (unsigned int)(cg << 4);
    int v0 = (blockIdx.x * 4 + w) * 4;          // nodes v0..v0+3
    const char* qsb = (const char*)qs;

    half2v qd2a[4], qd2b[4], qd2c[4], qd2d[4];
    {
        uint4 qA = ((const uint4*)qd)[(size_t)v0 * 8 + cg];
        uint4 qB = ((const uint4*)qd)[(size_t)(v0 + 1) * 8 + cg];
        uint4 qC = ((const uint4*)qd)[(size_t)(v0 + 2) * 8 + cg];
        uint4 qD = ((const uint4*)qd)[(size_t)(v0 + 3) * 8 + cg];
        unsigned int ua[4] = {qA.x, qA.y, qA.z, qA.w};
        unsigned int ub[4] = {qB.x, qB.y, qB.z, qB.w};
        unsigned int uc[4] = {qC.x, qC.y, qC.z, qC.w};
        unsigned int ud[4] = {qD.x, qD.y, qD.z, qD.w};
#pragma unroll
        for (int d = 0; d < 4; ++d) {
            qd2a[d] = bitcast_h2(ua[d]); qd2b[d] = bitcast_h2(ub[d]);
            qd2c[d] = bitcast_h2(uc[d]); qd2d[d] = bitcast_h2(ud[d]);
        }
    }

    float accA[8] = {0,0,0,0,0,0,0,0};
    float accB[8] = {0,0,0,0,0,0,0,0};
    float accC[8] = {0,0,0,0,0,0,0,0};
    float accD[8] = {0,0,0,0,0,0,0,0};
    int rs0 = rowstart[v0], rs1 = rowstart[v0 + 1], rs2 = rowstart[v0 + 2];
    int rs3 = rowstart[v0 + 3], rs4 = rowstart[v0 + 4];
    if (es == 0) {  // self loops (8 lanes, 4 sequential rows)
        accum8f(qsb, ((unsigned int)(v0 << 7)) | cg16, qd2a, accA);
        accum8f(qsb, ((unsigned int)((v0 + 1) << 7)) | cg16, qd2b, accB);
        accum8f(qsb, ((unsigned int)((v0 + 2) << 7)) | cg16, qd2c, accC);
        accum8f(qsb, ((unsigned int)((v0 + 3) << 7)) | cg16, qd2d, accD);
    }
    quad_edge_loop(qsb, colsrc, rs0, rs1, rs1, rs2, rs2, rs3, rs3, rs4,
                   lane, es, cg16, qd2a, qd2b, qd2c, qd2d, accA, accB, accC, accD);

    float degA = (float)(rs1 - rs0 + 1);
    float degB = (float)(rs2 - rs1 + 1);
    float degC = (float)(rs3 - rs2 + 1);
    float degD = (float)(rs4 - rs3 + 1);
#pragma unroll
    for (int j = 0; j < 3; ++j) {
        float tA = 0.f, tB = 0.f, tC = 0.f, tD = 0.f;
#pragma unroll
        for (int k = 0; k < 8; ++k) {
            float wv = w2c[j][cg * 8 + k];
            tA += accA[k] * wv; tB += accB[k] * wv;
            tC += accC[k] * wv; tD += accD[k] * wv;
        }
#pragma unroll
        for (int st = 1; st <= 32; st <<= 1) {
            tA += __shfl_xor(tA, st); tB += __shfl_xor(tB, st);
            tC += __shfl_xor(tC, st); tD += __shfl_xor(tD, st);
        }
        if (lane == 0) {
            float vA = tA + degA * b2c[j];
            float vB = tB + degB * b2c[j];
            float vC = tC + degC * b2c[j];
            float vD = tD + degD * b2c[j];
            pnext[v0 * 3 + j] = vA;
            pnext[(v0 + 1) * 3 + j] = vB;
            pnext[(v0 + 2) * 3 + j] = vC;
            pnext[(v0 + 3) * 3 + j] = vD;
            part[w][j] = vA + vB + vC + vD;
            part[w][3 + j] = vA * vA + vB * vB + vC * vC + vD * vD;
        }
    }
    __syncthreads();
    if (tid < 6) {
        float ssum = part[0][tid] + part[1][tid] + part[2][tid] + part[3][tid];
        atomicAdd(&gsum_l[(blockIdx.x & (NSLOT - 1)) * 8 + tid], ssum);
    }
}

// ---------------- gather + full 64-col matmul, layer 5, 4 nodes/wave ----------------
__global__ __launch_bounds__(256) void k_gather_full(
    const __half* __restrict__ qs, const __half* __restrict__ qd,
    const int* __restrict__ rowstart, const ushort_t* __restrict__ colsrc,
    const float* __restrict__ W2l, const float* __restrict__ b2l,
    float* __restrict__ out) {
    __shared__ float lds[4][4][64];
    int tid = threadIdx.x;
    int w = tid >> 6, lane = tid & 63;
    int es = lane >> 3, cg = lane & 7;
    unsigned int cg16 = (unsigned int)(cg << 4);
    int v0 = (blockIdx.x * 4 + w) * 4;
    const char* qsb = (const char*)qs;

    half2v qd2a[4], qd2b[4], qd2c[4], qd2d[4];
    {
        uint4 qA = ((const uint4*)qd)[(size_t)v0 * 8 + cg];
        uint4 qB = ((const uint4*)qd)[(size_t)(v0 + 1) * 8 + cg];
        uint4 qC = ((const uint4*)qd)[(size_t)(v0 + 2) * 8 + cg];
        uint4 qD = ((const uint4*)qd)[(size_t)(v0 + 3) * 8 + cg];
        unsigned int ua[4] = {qA.x, qA.y, qA.z, qA.w};
        unsigned int ub[4] = {qB.x, qB.y, qB.z, qB.w};
        unsigned int uc[4] = {qC.x, qC.y, qC.z, qC.w};
        unsigned int ud[4] = {qD.x, qD.y, qD.z, qD.w};
#pragma unroll
        for (int d = 0; d < 4; ++d) {
            qd2a[d] = bitcast_h2(ua[d]); qd2b[d] = bitcast_h2(ub[d]);
            qd2c[d] = bitcast_h2(uc[d]); qd2d[d] = bitcast_h2(ud[d]);
        }
    }

    float accA[8] = {0,0,0,0,0,0,0,0};
    float accB[8] = {0,0,0,0,0,0,0,0};
    float accC[8] = {0,0,0,0,0,0,0,0};
    float accD[8] = {0,0,0,0,0,0,0,0};
    int rs0 = rowstart[v0], rs1 = rowstart[v0 + 1], rs2 = rowstart[v0 + 2];
    int rs3 = rowstart[v0 + 3], rs4 = rowstart[v0 + 4];
    if (es == 0) {
        accum8f(qsb, ((unsigned int)(v0 << 7)) | cg16, qd2a, accA);
        accum8f(qsb, ((unsigned int)((v0 + 1) << 7)) | cg16, qd2b, accB);
        accum8f(qsb, ((unsigned int)((v0 + 2) << 7)) | cg16, qd2c, accC);
        accum8f(qsb, ((unsigned int)((v0 + 3) << 7)) | cg16, qd2d, accD);
    }
    quad_edge_loop(qsb, colsrc, rs0, rs1, rs1, rs2, rs2, rs3, rs3, rs4,
                   lane, es, cg16, qd2a, qd2b, qd2c, qd2d, accA, accB, accC, accD);

#pragma unroll
    for (int k = 0; k < 8; ++k) {
#pragma unroll
        for (int st = 8; st <= 32; st <<= 1) {
            accA[k] += __shfl_xor(accA[k], st);
            accB[k] += __shfl_xor(accB[k], st);
            accC[k] += __shfl_xor(accC[k], st);
            accD[k] += __shfl_xor(accD[k], st);
        }
    }
    if (es == 0) {
#pragma unroll
        for (int k = 0; k < 8; ++k) {
            lds[w][0][cg * 8 + k] = accA[k];
            lds[w][1][cg * 8 + k] = accB[k];
            lds[w][2][cg * 8 + k] = accC[k];
            lds[w][3][cg * 8 + k] = accD[k];
        }
    }
    __syncthreads();
    float bl = b2l[lane];
    float sumA = (float)(rs1 - rs0 + 1) * bl;
    float sumB = (float)(rs2 - rs1 + 1) * bl;
    float sumC = (float)(rs3 - rs2 + 1) * bl;
    float sumD = (float)(rs4 - rs3 + 1) * bl;
    for (int k = 0; k < 64; ++k) {
        float wv = W2l[k * 64 + lane];
        sumA += lds[w][0][k] * wv;
        sumB += lds[w][1][k] * wv;
        sumC += lds[w][2][k] * wv;
        sumD += lds[w][3][k] * wv;
    }
    out[(size_t)v0 * 64 + lane] = sumA;
    out[(size_t)(v0 + 1) * 64 + lane] = sumB;
    out[(size_t)(v0 + 2) * 64 + lane] = sumC;
    out[(size_t)(v0 + 3) * 64 + lane] = sumD;
}

// ---------------- launch ----------------

static inline size_t align_up(size_t x) { return (x + 255) & ~(size_t)255; }

extern "C" void kernel_launch(void* const* d_in, const int* in_sizes, int n_in,
                              void* d_out, int out_size, void* d_ws, size_t ws_size,
                              hipStream_t stream) {
    const float* x     = (const float*)d_in[0];
    const int*   ei    = (const int*)d_in[1];
    const float* W1    = (const float*)d_in[2];
    const float* b1    = (const float*)d_in[3];
    const float* W2    = (const float*)d_in[4];
    const float* b2    = (const float*)d_in[5];
    const float* gamma = (const float*)d_in[6];
    const float* beta  = (const float*)d_in[7];
    float* out = (float*)d_out;
    const int E = in_sizes[1] / 2;           // 1,600,000
    const int* src = ei;
    const int* dst = ei + E;

    const int nchunk = (E + CHUNK - 1) / CHUNK;     // 391
    const int nscan  = NBKT * nchunk;
    const int nsb    = (nscan + 255) / 256;

    // workspace carve
    char* base = (char*)d_ws;
    size_t off = 0;
    __half* qs = (__half*)(base + off);     off = align_up(off + (size_t)NN * 64 * 2);
    __half* qd = (__half*)(base + off);     off = align_up(off + (size_t)NN * 64 * 2);
    float* pA = (float*)(base + off);       off = align_up(off + (size_t)NN * 3 * 4);
    float* pB = (float*)(base + off);       off = align_up(off + (size_t)NN * 3 * 4);
    int* rowstart = (int*)(base + off);     off = align_up(off + (size_t)(NN + 1) * 4);
    ushort_t* colsrc = (ushort_t*)(base + off); off = align_up(off + (size_t)E * 2);
    int* ebuf     = (int*)(base + off);     off = align_up(off + (size_t)E * 4);
    int* hist     = (int*)(base + off);     off = align_up(off + (size_t)nscan * 4);
    int* offsT    = (int*)(base + off);     off = align_up(off + (size_t)nscan * 4);
    int* presum   = (int*)(base + off);     off = align_up(off + (size_t)nscan * 4);
    int* bsum     = (int*)(base + off);     off = align_up(off + (size_t)nsb * 4);
    float* gsumsp = (float*)(base + off);   off = align_up(off + (size_t)5 * NSLOT * 8 * 4);
    (void)ws_size; (void)n_in; (void)out_size;

    // CSR build: two-stage counting sort, no hot-line atomics (also zeros gsumsp)
    k_hist1<<<nchunk, 256, 0, stream>>>(dst, E, nchunk, hist, gsumsp);
    k_scanA<<<nsb, 256, 0, stream>>>(hist, nscan, presum, bsum);
    k_scanC<<<nsb, 256, 0, stream>>>(presum, hist, bsum, nscan, nchunk, offsT);
    k_scatter1<<<nchunk, 256, 0, stream>>>(src, dst, E, offsT, ebuf);
    k_bucket_csr<<<NBKT, 256, 0, stream>>>(ebuf, offsT, E, rowstart, colsrc);

    float* pc = pA;
    float* pn = pB;
    for (int l = 0; l < 6; ++l) {
        const float* pin = (l == 0) ? x : pc;
        int pstride = (l == 0) ? 16 : 3;
        int c0 = 0, c1 = 1, c2 = (l == 0) ? 14 : 2;
        const float* gsum_prev = (l == 0) ? gsumsp : gsumsp + (size_t)(l - 1) * NSLOT * 8;
        const float* gamma_prev = (l == 0) ? gamma : gamma + (size_t)(l - 1) * 64;
        const float* beta_prev  = (l == 0) ? beta  : beta  + (size_t)(l - 1) * 64;
        k_q<<<NQBLK8, 256, 0, stream>>>(pin, pstride, c0, c1, c2,
                                        W1 + (size_t)l * 6 * 64, b1 + (size_t)l * 64,
                                        gsum_prev, gamma_prev, beta_prev,
                                        (l > 0) ? 1 : 0, qs, qd);
        if (l < 5) {
            k_gather3<<<NGBLK4, 256, 0, stream>>>(qs, qd, rowstart, colsrc,
                                                  W2 + (size_t)l * 64 * 64, b2 + (size_t)l * 64,
                                                  pn, gsumsp + (size_t)l * NSLOT * 8);
            float* tmp = pc; pc = pn; pn = tmp;
        } else {
            k_gather_full<<<NGBLK4, 256, 0, stream>>>(qs, qd, rowstart, colsrc,
                                                      W2 + (size_t)5 * 64 * 64, b2 + (size_t)5 * 64,
                                                      out);
        }
    }
}

// Round 9
// 407.230 us; speedup vs baseline: 1.2069x; 1.2069x over previous
//
#include <hip/hip_runtime.h>
#include <hip/hip_fp16.h>
#include <cstdint>

#define NN 50000
#define NQBLK8 1563             // k_q blocks: NN*8/256 rounded up
#define NGBLKW 12500            // gather blocks: 128 thr = 2 waves x 2 nodes = 4 nodes/block
#define EPSV 1e-5f

// bucket sort params
#define NPB 128                 // nodes per bucket
#define BSH 7                   // log2(NPB)
#define NBKT 391                // ceil(NN/NPB)
#define CHUNK 4096              // edges per stage-1 block
#define EPT 16                  // edges per thread (CHUNK/256)
#define LDSE 6144               // per-bucket LDS edge capacity

// BN partial-sum spreading: 128 slots x 8 floats per layer (64 cache lines).
// R9/R10: hot-line atomics cost ~120us; spread over 64 lines -> negligible.
#define NSLOT 128

typedef unsigned short ushort_t;
typedef _Float16 half2v __attribute__((ext_vector_type(2)));

// ---------------- stage 1: per-chunk bucket histogram (+ zero BN slots) ----------------
__global__ __launch_bounds__(256) void k_hist1(const int* __restrict__ dst, int E, int nchunk,
                                               int* __restrict__ hist, float* __restrict__ gsumsp) {
    __shared__ int cnt[NBKT];
    int t = threadIdx.x, blk = blockIdx.x;
    if (blk == 0) {
        for (int z = t; z < 5 * NSLOT * 8; z += 256) gsumsp[z] = 0.f;
    }
    for (int b = t; b < NBKT; b += 256) cnt[b] = 0;
    __syncthreads();
    int base = blk * CHUNK;
#pragma unroll
    for (int k = 0; k < EPT; ++k) {
        int e = base + k * 256 + t;
        if (e < E) atomicAdd(&cnt[dst[e] >> BSH], 1);
    }
    __syncthreads();
    for (int b = t; b < NBKT; b += 256) hist[(size_t)b * nchunk + blk] = cnt[b];
}

// ---------------- hierarchical exclusive scan (A: per-block, C: fused apply) ----------------
__global__ __launch_bounds__(256) void k_scanA(const int* __restrict__ in, int n,
                                               int* __restrict__ presum, int* __restrict__ blocksum) {
    __shared__ int lds[256];
    int t = threadIdx.x, g = blockIdx.x * 256 + t;
    int v = (g < n) ? in[g] : 0;
    lds[t] = v;
    __syncthreads();
    for (int off = 1; off < 256; off <<= 1) {
        int x = (t >= off) ? lds[t - off] : 0;
        __syncthreads();
        lds[t] += x;
        __syncthreads();
    }
    if (g < n) presum[g] = lds[t];
    if (t == 255) blocksum[blockIdx.x] = lds[255];
}

// fused scanB+scanC: each block computes its own carry (sum of blocksum[0..blk))
__global__ __launch_bounds__(256) void k_scanC(const int* __restrict__ presum,
                                               const int* __restrict__ hist,
                                               const int* __restrict__ blocksum,
                                               int n, int nchunk, int* __restrict__ offsT) {
    __shared__ int lds[256];
    int t = threadIdx.x, myblk = blockIdx.x;
    int acc = 0;
    for (int i = t; i < myblk; i += 256) acc += blocksum[i];
    lds[t] = acc;
    __syncthreads();
    for (int off = 128; off > 0; off >>= 1) {
        if (t < off) lds[t] += lds[t + off];
        __syncthreads();
    }
    int boff = lds[0];
    int g = myblk * 256 + t;
    if (g < n) {
        int val = presum[g] - hist[g] + boff;
        int b = g / nchunk;
        int c = g - b * nchunk;
        offsT[(size_t)c * NBKT + b] = val;
    }
}

// ---------------- stage 1: partition edges into buckets ----------------
__global__ __launch_bounds__(256) void k_scatter1(const int* __restrict__ src,
                                                  const int* __restrict__ dst, int E,
                                                  const int* __restrict__ offsT,
                                                  int* __restrict__ ebuf) {
    __shared__ int pos[NBKT];
    int t = threadIdx.x, blk = blockIdx.x;
    for (int b = t; b < NBKT; b += 256) pos[b] = offsT[(size_t)blk * NBKT + b];
    __syncthreads();
    int base = blk * CHUNK;
#pragma unroll
    for (int k = 0; k < EPT; ++k) {
        int e = base + k * 256 + t;
        if (e < E) {
            int d = dst[e];
            int b = d >> BSH;
            int p = atomicAdd(&pos[b], 1);
            ebuf[p] = ((d & (NPB - 1)) << 16) | src[e];
        }
    }
}

// ---------------- stage 2: per-bucket CSR ----------------
__global__ __launch_bounds__(256) void k_bucket_csr(const int* __restrict__ ebuf,
                                                    const int* __restrict__ offsT, int E,
                                                    int* __restrict__ rowstart,
                                                    ushort_t* __restrict__ colsrc) {
    __shared__ int cnt[NPB];
    __shared__ int s[NPB];
    __shared__ int pos2[NPB];
    __shared__ ushort_t lout[LDSE];
    int t = threadIdx.x, b = blockIdx.x;
    int bstart = offsT[b];
    int bend = (b + 1 < NBKT) ? offsT[b + 1] : E;
    int m = bend - bstart;
    if (t < NPB) cnt[t] = 0;
    __syncthreads();
    for (int i = bstart + t; i < bend; i += 256) atomicAdd(&cnt[ebuf[i] >> 16], 1);
    __syncthreads();
    if (t < NPB) s[t] = cnt[t];
    __syncthreads();
    for (int off = 1; off < NPB; off <<= 1) {
        int x = (t < NPB && t >= off) ? s[t - off] : 0;
        __syncthreads();
        if (t < NPB) s[t] += x;
        __syncthreads();
    }
    if (t < NPB) {
        int excl = s[t] - cnt[t];
        int node = b * NPB + t;
        if (node < NN) rowstart[node] = bstart + excl;
        pos2[t] = excl;
    }
    __syncthreads();
    if (m <= LDSE) {
        for (int i = bstart + t; i < bend; i += 256) {
            int v = ebuf[i];
            int p = atomicAdd(&pos2[v >> 16], 1);
            lout[p] = (ushort_t)(v & 0xFFFF);
        }
        __syncthreads();
        for (int i = t; i < m; i += 256) colsrc[bstart + i] = lout[i];
    } else {
        for (int i = bstart + t; i < bend; i += 256) {
            int v = ebuf[i];
            int p = atomicAdd(&pos2[v >> 16], 1);
            colsrc[bstart + p] = (ushort_t)(v & 0xFFFF);
        }
    }
    if (b == NBKT - 1 && t == 0) rowstart[NN] = E;
}

// ---------------- per-layer: node -> (q_s, q_d), BN-finalize fused in-block ----------------
__global__ __launch_bounds__(256) void k_q(
    const float* __restrict__ pin, int pstride, int c0, int c1, int c2,
    const float* __restrict__ W1l, const float* __restrict__ b1l,
    const float* __restrict__ gsum_prev, const float* __restrict__ gamma_l,
    const float* __restrict__ beta_l, int use_bn,
    __half* __restrict__ qs, __half* __restrict__ qd) {
    __shared__ float red[6][8];
    __shared__ float scv[3], shv[3];
    int tid = threadIdx.x;
    if (use_bn) {
        if (tid < 48) {
            int j = tid >> 3, k = tid & 7;
            float s = 0.f;
            for (int slot = k; slot < NSLOT; slot += 8) s += gsum_prev[slot * 8 + j];
            red[j][k] = s;
        }
        __syncthreads();
        if (tid < 3) {
            const int cols[3] = {0, 1, 14};
            float sum = 0.f, sumsq = 0.f;
#pragma unroll
            for (int k2 = 0; k2 < 8; ++k2) { sum += red[tid][k2]; sumsq += red[tid + 3][k2]; }
            float mu = sum / (float)NN;
            float var = sumsq / (float)NN - mu * mu;
            float rs = rsqrtf(var + EPSV);
            float g = gamma_l[cols[tid]];
            scv[tid] = rs * g;
            shv[tid] = beta_l[cols[tid]] - mu * rs * g;
        }
        __syncthreads();
    }
    int idx = blockIdx.x * 256 + tid;
    int v = idx >> 3, g = idx & 7;
    if (v >= NN) return;
    const float* prow = pin + (size_t)v * pstride;
    float p0 = prow[c0], p1 = prow[c1], p2 = prow[c2];
    if (use_bn) {
        p0 = fmaxf(0.f, p0 * scv[0] + shv[0]);
        p1 = fmaxf(0.f, p1 * scv[1] + shv[1]);
        p2 = fmaxf(0.f, p2 * scv[2] + shv[2]);
    }
    unsigned int us[4], ud[4];
#pragma unroll
    for (int pr = 0; pr < 4; ++pr) {
        int c = (g << 3) + (pr << 1);
        float w0a = W1l[c], w1a = W1l[64 + c], w2a = W1l[128 + c];
        float qsa = p0 * w0a + p1 * w1a + p2 * w2a;
        float qda = p0 * (W1l[192 + c] - w0a) + p1 * (W1l[256 + c] - w1a)
                  + p2 * (W1l[320 + c] - w2a) + b1l[c];
        int c1i = c + 1;
        float w0b = W1l[c1i], w1b = W1l[64 + c1i], w2b = W1l[128 + c1i];
        float qsb = p0 * w0b + p1 * w1b + p2 * w2b;
        float qdb = p0 * (W1l[192 + c1i] - w0b) + p1 * (W1l[256 + c1i] - w1b)
                  + p2 * (W1l[320 + c1i] - w2b) + b1l[c1i];
        us[pr] = (unsigned int)__half_as_ushort(__float2half(qsa))
               | ((unsigned int)__half_as_ushort(__float2half(qsb)) << 16);
        ud[pr] = (unsigned int)__half_as_ushort(__float2half(qda))
               | ((unsigned int)__half_as_ushort(__float2half(qdb)) << 16);
    }
    uint4 vs = {us[0], us[1], us[2], us[3]};
    uint4 vd = {ud[0], ud[1], ud[2], ud[3]};
    ((uint4*)qs)[(size_t)v * 8 + g] = vs;
    ((uint4*)qd)[(size_t)v * 8 + g] = vd;
}

// ---------------- edge accumulation helpers (R19 form — proven best) ----------------
// R9: no per-load branches; masked slots load row 0. R13: no device fences.
// R18: two nodes per wave (paired clauses, 8 loads in flight).
// R19: next iteration's colsrc prefetched before math.
// R22: 128-thread (2-wave) workgroups -> 12500 blocks, finer CU balancing
// (R21 lesson: throughput ~ resident waves; R20's 3125 coarse blocks lost occ).
__device__ __forceinline__ half2v bitcast_h2(unsigned int u) {
    union { unsigned int u; half2v h; } cvt;
    cvt.u = u;
    return cvt.h;
}

__device__ __forceinline__ void accum8f(const char* __restrict__ qsb, unsigned int byteoff,
                                        const half2v qd2[4], float acc[8]) {
    uint4 q = *reinterpret_cast<const uint4*>(qsb + byteoff);
    unsigned int wd[4] = {q.x, q.y, q.z, q.w};
    const half2v z2 = {(_Float16)0.0f, (_Float16)0.0f};
#pragma unroll
    for (int d = 0; d < 4; ++d) {
        half2v r = bitcast_h2(wd[d]) + qd2[d];
        r = __builtin_elementwise_max(r, z2);
        acc[2 * d]     += (float)r.x;
        acc[2 * d + 1] += (float)r.y;
    }
}

__device__ __forceinline__ void chunk_math32(const uint4 q[4], const half2v qd2[4],
                                             int r, int es, float acc[8]) {
    const half2v z2 = {(_Float16)0.0f, (_Float16)0.0f};
    half2v h[4] = {z2, z2, z2, z2};
#pragma unroll
    for (int k = 0; k < 4; ++k) {
        bool ok = ((k << 3) + es) < r;
        unsigned int wd[4] = {q[k].x, q[k].y, q[k].z, q[k].w};
#pragma unroll
        for (int d = 0; d < 4; ++d) {
            half2v t = bitcast_h2(wd[d]) + qd2[d];      // v_pk_add_f16
            t = __builtin_elementwise_max(t, z2);       // v_pk_max_f16
            h[d] += ok ? t : z2;                        // cndmask + pk_add
        }
    }
#pragma unroll
    for (int d = 0; d < 4; ++d) {
        acc[2 * d]     += (float)h[d].x;
        acc[2 * d + 1] += (float)h[d].y;
    }
}

__device__ __forceinline__ int clamp32v(int x) { return x < 32 ? (x < 0 ? 0 : x) : 32; }

// paired + pipelined loop: nodes A [iA,e0) and B [iB,e1)
__device__ __forceinline__ void pair_edge_loop(const char* __restrict__ qsb,
                                               const ushort_t* __restrict__ colsrc,
                                               int iA, int e0, int iB, int e1,
                                               int lane, int es, unsigned int cg16,
                                               const half2v qd2A[4], const half2v qd2B[4],
                                               float accA[8], float accB[8]) {
    int rA = clamp32v(e0 - iA);
    int rB = clamp32v(e1 - iB);
    if (rA == 0 && rB == 0) return;
    int slA = (lane < rA) ? (int)colsrc[iA + lane] : 0;
    int slB = (lane < rB) ? (int)colsrc[iB + lane] : 0;
    while (true) {
        uint4 qA[4], qB[4];
#pragma unroll
        for (int k = 0; k < 4; ++k) {
            int s = __shfl(slA, (k << 3) + es);
            qA[k] = *reinterpret_cast<const uint4*>(qsb + (((unsigned int)(s << 7)) | cg16));
        }
#pragma unroll
        for (int k = 0; k < 4; ++k) {
            int s = __shfl(slB, (k << 3) + es);
            qB[k] = *reinterpret_cast<const uint4*>(qsb + (((unsigned int)(s << 7)) | cg16));
        }
        int iA2 = iA + rA, iB2 = iB + rB;
        int rA2 = clamp32v(e0 - iA2);
        int rB2 = clamp32v(e1 - iB2);
        bool more = (rA2 > 0) || (rB2 > 0);
        int slA2 = 0, slB2 = 0;
        if (more) {     // wave-uniform; prefetch next colsrc words before math
            slA2 = (lane < rA2) ? (int)colsrc[iA2 + lane] : 0;
            slB2 = (lane < rB2) ? (int)colsrc[iB2 + lane] : 0;
        }
        chunk_math32(qA, qd2A, rA, es, accA);
        chunk_math32(qB, qd2B, rB, es, accB);
        if (!more) break;
        iA = iA2; iB = iB2; rA = rA2; rB = rB2; slA = slA2; slB = slB2;
    }
}

// ---------------- gather + reduce, layers 0..4 (3 output cols), 2 nodes/wave ----------------
__global__ __launch_bounds__(128, 4) void k_gather3(
    const __half* __restrict__ qs, const __half* __restrict__ qd,
    const int* __restrict__ rowstart, const ushort_t* __restrict__ colsrc,
    const float* __restrict__ W2l, const float* __restrict__ b2l,
    float* __restrict__ pnext, float* __restrict__ gsum_l) {
    __shared__ float w2c[3][64];
    __shared__ float b2c[3];
    __shared__ float part[2][8];
    int tid = threadIdx.x;
    for (int i = tid; i < 192; i += 128) {
        int cj = i >> 6;
        int col = (cj == 0) ? 0 : ((cj == 1) ? 1 : 14);
        w2c[cj][i & 63] = W2l[(i & 63) * 64 + col];
    }
    if (tid < 3) b2c[tid] = b2l[(tid == 0) ? 0 : ((tid == 1) ? 1 : 14)];
    __syncthreads();

    int w = tid >> 6, lane = tid & 63;          // w in {0,1}
    int es = lane >> 3, cg = lane & 7;
    unsigned int cg16 = (unsigned int)(cg << 4);
    int v0 = (blockIdx.x * 2 + w) * 2;          // nodes v0, v0+1
    const char* qsb = (const char*)qs;

    uint4 qqA = ((const uint4*)qd)[(size_t)v0 * 8 + cg];
    uint4 qqB = ((const uint4*)qd)[(size_t)(v0 + 1) * 8 + cg];
    half2v qd2A[4], qd2B[4];
    {
        unsigned int qa[4] = {qqA.x, qqA.y, qqA.z, qqA.w};
        unsigned int qb[4] = {qqB.x, qqB.y, qqB.z, qqB.w};
#pragma unroll
        for (int d = 0; d < 4; ++d) { qd2A[d] = bitcast_h2(qa[d]); qd2B[d] = bitcast_h2(qb[d]); }
    }

    float accA[8] = {0, 0, 0, 0, 0, 0, 0, 0};
    float accB[8] = {0, 0, 0, 0, 0, 0, 0, 0};
    int s0 = rowstart[v0], e0 = rowstart[v0 + 1], e1 = rowstart[v0 + 2];
    if (es == 0) {  // self loops
        accum8f(qsb, ((unsigned int)(v0 << 7)) | cg16, qd2A, accA);
        accum8f(qsb, ((unsigned int)((v0 + 1) << 7)) | cg16, qd2B, accB);
    }
    pair_edge_loop(qsb, colsrc, s0, e0, e0, e1, lane, es, cg16, qd2A, qd2B, accA, accB);

    // project unfolded partials through the 3 W2 columns, fold all 6 strides
    float degA = (float)(e0 - s0 + 1);
    float degB = (float)(e1 - e0 + 1);
#pragma unroll
    for (int j = 0; j < 3; ++j) {
        float tA = 0.f, tB = 0.f;
#pragma unroll
        for (int k = 0; k < 8; ++k) {
            float wv = w2c[j][cg * 8 + k];
            tA += accA[k] * wv;
            tB += accB[k] * wv;
        }
        tA += __shfl_xor(tA, 1);  tB += __shfl_xor(tB, 1);
        tA += __shfl_xor(tA, 2);  tB += __shfl_xor(tB, 2);
        tA += __shfl_xor(tA, 4);  tB += __shfl_xor(tB, 4);
        tA += __shfl_xor(tA, 8);  tB += __shfl_xor(tB, 8);
        tA += __shfl_xor(tA, 16); tB += __shfl_xor(tB, 16);
        tA += __shfl_xor(tA, 32); tB += __shfl_xor(tB, 32);
        if (lane == 0) {
            float valA = tA + degA * b2c[j];
            float valB = tB + degB * b2c[j];
            pnext[v0 * 3 + j] = valA;
            pnext[(v0 + 1) * 3 + j] = valB;
            part[w][j] = valA + valB;
            part[w][3 + j] = valA * valA + valB * valB;
        }
    }
    __syncthreads();
    if (tid < 6) {
        float ssum = part[0][tid] + part[1][tid];
        atomicAdd(&gsum_l[(blockIdx.x & (NSLOT - 1)) * 8 + tid], ssum);
    }
}

// ---------------- gather + full 64-col matmul, layer 5, 2 nodes/wave ----------------
__global__ __launch_bounds__(128, 4) void k_gather_full(
    const __half* __restrict__ qs, const __half* __restrict__ qd,
    const int* __restrict__ rowstart, const ushort_t* __restrict__ colsrc,
    const float* __restrict__ W2l, const float* __restrict__ b2l,
    float* __restrict__ out) {
    __shared__ float lds[2][2][64];
    int tid = threadIdx.x;
    int w = tid >> 6, lane = tid & 63;
    int es = lane >> 3, cg = lane & 7;
    unsigned int cg16 = (unsigned int)(cg << 4);
    int v0 = (blockIdx.x * 2 + w) * 2;
    const char* qsb = (const char*)qs;

    uint4 qqA = ((const uint4*)qd)[(size_t)v0 * 8 + cg];
    uint4 qqB = ((const uint4*)qd)[(size_t)(v0 + 1) * 8 + cg];
    half2v qd2A[4], qd2B[4];
    {
        unsigned int qa[4] = {qqA.x, qqA.y, qqA.z, qqA.w};
        unsigned int qb[4] = {qqB.x, qqB.y, qqB.z, qqB.w};
#pragma unroll
        for (int d = 0; d < 4; ++d) { qd2A[d] = bitcast_h2(qa[d]); qd2B[d] = bitcast_h2(qb[d]); }
    }

    float accA[8] = {0, 0, 0, 0, 0, 0, 0, 0};
    float accB[8] = {0, 0, 0, 0, 0, 0, 0, 0};
    int s0 = rowstart[v0], e0 = rowstart[v0 + 1], e1 = rowstart[v0 + 2];
    if (es == 0) {
        accum8f(qsb, ((unsigned int)(v0 << 7)) | cg16, qd2A, accA);
        accum8f(qsb, ((unsigned int)((v0 + 1) << 7)) | cg16, qd2B, accB);
    }
    pair_edge_loop(qsb, colsrc, s0, e0, e0, e1, lane, es, cg16, qd2A, qd2B, accA, accB);

#pragma unroll
    for (int k = 0; k < 8; ++k) {
        accA[k] += __shfl_xor(accA[k], 8);
        accA[k] += __shfl_xor(accA[k], 16);
        accA[k] += __shfl_xor(accA[k], 32);
        accB[k] += __shfl_xor(accB[k], 8);
        accB[k] += __shfl_xor(accB[k], 16);
        accB[k] += __shfl_xor(accB[k], 32);
    }
    if (es == 0) {
#pragma unroll
        for (int k = 0; k < 8; ++k) {
            lds[w][0][cg * 8 + k] = accA[k];
            lds[w][1][cg * 8 + k] = accB[k];
        }
    }
    __syncthreads();
    float degA = (float)(e0 - s0 + 1);
    float degB = (float)(e1 - e0 + 1);
    float bl = b2l[lane];
    float sumA = degA * bl;
    float sumB = degB * bl;
    for (int k = 0; k < 64; ++k) {
        float wv = W2l[k * 64 + lane];
        sumA += lds[w][0][k] * wv;
        sumB += lds[w][1][k] * wv;
    }
    out[(size_t)v0 * 64 + lane] = sumA;
    out[(size_t)(v0 + 1) * 64 + lane] = sumB;
}

// ---------------- launch ----------------

static inline size_t align_up(size_t x) { return (x + 255) & ~(size_t)255; }

extern "C" void kernel_launch(void* const* d_in, const int* in_sizes, int n_in,
                              void* d_out, int out_size, void* d_ws, size_t ws_size,
                              hipStream_t stream) {
    const float* x     = (const float*)d_in[0];
    const int*   ei    = (const int*)d_in[1];
    const float* W1    = (const float*)d_in[2];
    const float* b1    = (const float*)d_in[3];
    const float* W2    = (const float*)d_in[4];
    const float* b2    = (const float*)d_in[5];
    const float* gamma = (const float*)d_in[6];
    const float* beta  = (const float*)d_in[7];
    float* out = (float*)d_out;
    const int E = in_sizes[1] / 2;           // 1,600,000
    const int* src = ei;
    const int* dst = ei + E;

    const int nchunk = (E + CHUNK - 1) / CHUNK;     // 391
    const int nscan  = NBKT * nchunk;
    const int nsb    = (nscan + 255) / 256;

    // workspace carve
    char* base = (char*)d_ws;
    size_t off = 0;
    __half* qs = (__half*)(base + off);     off = align_up(off + (size_t)NN * 64 * 2);
    __half* qd = (__half*)(base + off);     off = align_up(off + (size_t)NN * 64 * 2);
    float* pA = (float*)(base + off);       off = align_up(off + (size_t)NN * 3 * 4);
    float* pB = (float*)(base + off);       off = align_up(off + (size_t)NN * 3 * 4);
    int* rowstart = (int*)(base + off);     off = align_up(off + (size_t)(NN + 1) * 4);
    ushort_t* colsrc = (ushort_t*)(base + off); off = align_up(off + (size_t)E * 2);
    int* ebuf     = (int*)(base + off);     off = align_up(off + (size_t)E * 4);
    int* hist     = (int*)(base + off);     off = align_up(off + (size_t)nscan * 4);
    int* offsT    = (int*)(base + off);     off = align_up(off + (size_t)nscan * 4);
    int* presum   = (int*)(base + off);     off = align_up(off + (size_t)nscan * 4);
    int* bsum     = (int*)(base + off);     off = align_up(off + (size_t)nsb * 4);
    float* gsumsp = (float*)(base + off);   off = align_up(off + (size_t)5 * NSLOT * 8 * 4);
    (void)ws_size; (void)n_in; (void)out_size;

    // CSR build: two-stage counting sort, no hot-line atomics (also zeros gsumsp)
    k_hist1<<<nchunk, 256, 0, stream>>>(dst, E, nchunk, hist, gsumsp);
    k_scanA<<<nsb, 256, 0, stream>>>(hist, nscan, presum, bsum);
    k_scanC<<<nsb, 256, 0, stream>>>(presum, hist, bsum, nscan, nchunk, offsT);
    k_scatter1<<<nchunk, 256, 0, stream>>>(src, dst, E, offsT, ebuf);
    k_bucket_csr<<<NBKT, 256, 0, stream>>>(ebuf, offsT, E, rowstart, colsrc);

    float* pc = pA;
    float* pn = pB;
    for (int l = 0; l < 6; ++l) {
        const float* pin = (l == 0) ? x : pc;
        int pstride = (l == 0) ? 16 : 3;
        int c0 = 0, c1 = 1, c2 = (l == 0) ? 14 : 2;
        const float* gsum_prev = (l == 0) ? gsumsp : gsumsp + (size_t)(l - 1) * NSLOT * 8;
        const float* gamma_prev = (l == 0) ? gamma : gamma + (size_t)(l - 1) * 64;
        const float* beta_prev  = (l == 0) ? beta  : beta  + (size_t)(l - 1) * 64;
        k_q<<<NQBLK8, 256, 0, stream>>>(pin, pstride, c0, c1, c2,
                                        W1 + (size_t)l * 6 * 64, b1 + (size_t)l * 64,
                                        gsum_prev, gamma_prev, beta_prev,
                                        (l > 0) ? 1 : 0, qs, qd);
        if (l < 5) {
            k_gather3<<<NGBLKW, 128, 0, stream>>>(qs, qd, rowstart, colsrc,
                                                  W2 + (size_t)l * 64 * 64, b2 + (size_t)l * 64,
                                                  pn, gsumsp + (size_t)l * NSLOT * 8);
            float* tmp = pc; pc = pn; pn = tmp;
        } else {
            k_gather_full<<<NGBLKW, 128, 0, stream>>>(qs, qd, rowstart, colsrc,
                                                      W2 + (size_t)5 * 64 * 64, b2 + (size_t)5 * 64,
                                                      out);
        }
    }
}